// Round 17
// baseline (2587.010 us; speedup 1.0000x reference)
//
#include <hip/hip_runtime.h>
#include <hip/hip_bf16.h>
#include <stdint.h>

#define NB 256
#define PERIOD 30

typedef __bf16  bf16x8 __attribute__((ext_vector_type(8)));
typedef float   f32x4  __attribute__((ext_vector_type(4)));
typedef float   f32x2  __attribute__((ext_vector_type(2)));
typedef unsigned int uint4v __attribute__((ext_vector_type(4)));

__device__ __forceinline__ float frcp(float x){ return __builtin_amdgcn_rcpf(x); }

// tanh(x) = 1 - 2/(exp(2x)+1)
__device__ __forceinline__ float fast_tanh(float x){
  float e = __expf(2.0f*x);
  return fmaf(-2.0f, frcp(e + 1.0f), 1.0f);
}

__device__ __forceinline__ unsigned int f2bfbits(float x){
  union { __hip_bfloat16 b; unsigned short u; } v;
  v.b = __float2bfloat16(x);          // RNE, matches XLA convert
  return (unsigned int)v.u;
}
__device__ __forceinline__ unsigned int pack2bf(float lo, float hi){
  return f2bfbits(lo) | (f2bfbits(hi) << 16);
}

// Threefry-2x32, 20 rounds, key = (0, 42)
__device__ __forceinline__ void threefry2x32_k42(uint32_t x0, uint32_t x1,
                                                 uint32_t& o0, uint32_t& o1){
  const uint32_t ks0 = 0u, ks1 = 42u, ks2 = 0u ^ 42u ^ 0x1BD11BDAu;
  x0 += ks0; x1 += ks1;
#define TFR(rot) { x0 += x1; x1 = (x1 << (rot)) | (x1 >> (32 - (rot))); x1 ^= x0; }
  TFR(13) TFR(15) TFR(26) TFR(6)
  x0 += ks1; x1 += ks2 + 1u;
  TFR(17) TFR(29) TFR(16) TFR(24)
  x0 += ks2; x1 += ks0 + 2u;
  TFR(13) TFR(15) TFR(26) TFR(6)
  x0 += ks0; x1 += ks1 + 3u;
  TFR(17) TFR(29) TFR(16) TFR(24)
  x0 += ks1; x1 += ks2 + 4u;
  TFR(13) TFR(15) TFR(26) TFR(6)
  x0 += ks2; x1 += ks0 + 5u;
#undef TFR
  o0 = x0; o1 = x1;
}

// Mirror jax.random.normal f32 (XLA erfinv polynomial)
__device__ __forceinline__ float normal_from_bits(uint32_t bits){
  float f = __uint_as_float((bits >> 9) | 0x3f800000u) - 1.0f;
  const float lo = -0.99999994f;
  float u = fmaf(f, 2.0f, lo);
  u = fmaxf(u, lo);
  float w = -log1pf(-u*u);
  float p;
  if (w < 5.0f){
    float ww = w - 2.5f;
    p = 2.81022636e-08f;
    p = fmaf(p, ww, 3.43273939e-07f);
    p = fmaf(p, ww, -3.5233877e-06f);
    p = fmaf(p, ww, -4.39150654e-06f);
    p = fmaf(p, ww, 0.00021858087f);
    p = fmaf(p, ww, -0.00125372503f);
    p = fmaf(p, ww, -0.00417768164f);
    p = fmaf(p, ww, 0.246640727f);
    p = fmaf(p, ww, 1.50140941f);
  } else {
    float ww = sqrtf(w) - 3.0f;
    p = -0.000200214257f;
    p = fmaf(p, ww, 0.000100950558f);
    p = fmaf(p, ww, 0.00134934322f);
    p = fmaf(p, ww, -0.00367342844f);
    p = fmaf(p, ww, 0.00573950773f);
    p = fmaf(p, ww, -0.0076224613f);
    p = fmaf(p, ww, 0.00943887047f);
    p = fmaf(p, ww, 1.00167406f);
    p = fmaf(p, ww, 2.83297682f);
  }
  return 1.41421356f * (p * u);
}

// stage one sample-tile's h/u rows (owners = lanes with grp==tile)
__device__ __forceinline__ void stage_tile(char* buf, int tile, int grp, int colL,
    const unsigned int* hp, const unsigned int* up){
  if (grp == tile){
    const int rbase = colL * 128;
    const int sw = (colL & 7) << 4;
#pragma unroll
    for (int w = 0; w < 8; ++w){
      int off = rbase + ((w * 16) ^ sw);
      *(uint4v*)(buf + off)        = uint4v{hp[w*4], hp[w*4+1], hp[w*4+2], hp[w*4+3]};
      *(uint4v*)(buf + 2048 + off) = uint4v{up[w*4], up[w*4+1], up[w*4+2], up[w*4+3]};
    }
  }
}

// step math (mirror reference, f32): given state + noise -> new q/Y
__device__ __forceinline__ void step_math(
    float dZ1, float dZ2,
    float q1, float q2, float q3, float Y2, float Y3,
    float s11, float s21, float s31, float s12, float s22, float s32,
    float& q1n, float& q2n, float& q3n, float& Y2n, float& Y3n)
{
  const float GAMMA = 1.2f, DT = 0.005f, SIGMA = 0.03f;
  const float KAPPA = 0.2f, YBAR = 2.0f, RHO = 0.03f, Bc = 1.0f, Cc = 0.1f;
  float Wt  = q1 + q2 + q3;
  float q1h = q1 / Wt;
  float q2h = q2 / Wt;
  float q3h = 1.0f - q1h - q2h;
  float q1sq = q1 * q1;
  float c   = Bc*q1 - Cc*q1sq + Y2 + Y3;
  float bq  = Bc*q1 - 2.0f*Cc*q1sq;
  float sc1 = fmaf(bq, s11, SIGMA);
  float sc2 = fmaf(bq, s12, SIGMA);
  float sW1 = q1*s11 + q2*s21 + q3*s31;
  float sW2 = q1*s12 + q2*s22 + q3*s32;
  float sJ1 = 6.0f * (sc1/c - sW1/Wt);
  float sJ2 = 6.0f * (sc2/c - sW2/Wt);
  float d11 = s11*s11 + s12*s12;
  float d12 = s11*s21 + s12*s22;
  float d13 = s11*s31 + s12*s32;
  float d22 = s21*s21 + s22*s22;
  float d23 = s21*s31 + s22*s32;
  float d33 = s31*s31 + s32*s32;
  const float oneMG = 1.0f - GAMMA;   // -0.2
  float p1 = GAMMA*(q1h*d11 + q2h*d12 + q3h*d13) - oneMG*(sJ1*s11 + sJ2*s12);
  float p2 = GAMMA*(q1h*d12 + q2h*d22 + q3h*d23) - oneMG*(sJ1*s21 + sJ2*s22);
  float p3 = GAMMA*(q1h*d13 + q2h*d23 + q3h*d33) - oneMG*(sJ1*s31 + sJ2*s32);
  float muY2 = KAPPA * (YBAR - Y2);
  float muY3 = KAPPA * (YBAR - Y3);
  float r = RHO + GAMMA*(bq*(p1 - (Bc - Cc*q1)) - Cc*q1sq*d11 + muY2 + muY3)/c
                - 1.32f*(sc1*sc1 + sc2*sc2)/(c*c);
  r = r / (1.0f - GAMMA*bq/c);
  float mu1 = r + p1 - (Bc - Cc*q1);
  float mu2 = r + p2 - Y2/q2;
  float mu3 = r + p3 - Y3/q3;
  q1n = q1 * (1.0f + mu1*DT + s11*dZ1 + s12*dZ2);
  q2n = q2 * (1.0f + mu2*DT + s21*dZ1 + s22*dZ2);
  q3n = q3 * (1.0f + mu3*DT + s31*dZ1 + s32*dZ2);
  Y2n = Y2 + muY2*DT + SIGMA*dZ1;
  Y3n = Y3 + muY3*DT + SIGMA*dZ2;
}

// MFMA net eval for TWO samples per thread (8 st-tiles). C[n, sample]
// orientation (R15). bh/wo: loaded per-hd at hd-top (zr defeats LICM — a
// 48-reg hoist on top of 128 pack regs would spill) and consumed only in the
// TAIL (tanh add), never as MFMA C-seed — R16 showed the C-seed put the LDS
// load latency on the critical path (−12%).
__device__ __forceinline__ void net_eval2(
    float y2a, float y3a, float y2b, float y3b,
    const float* __restrict__ W0, const float* __restrict__ b0,
    char* sAw, const char* __restrict__ sBb,
    const float* __restrict__ sBH, const float* __restrict__ sWO,
    int colL, int grp, const float* bo_v,
    float& q1a, float& q2a, float& q3a,
    float& s11a, float& s21a, float& s31a,
    float& s12a, float& s22a, float& s32a,
    float& q1b, float& q2b, float& q3b,
    float& s11b, float& s21b, float& s31b,
    float& s12b, float& s22b, float& s32b)
{
  // ---- first layer, both samples interleaved (2x ILP on tanh chains) ----
  unsigned int hp0[32], up0[32], hp1[32], up1[32];
#pragma unroll
  for (int d = 0; d < 32; ++d){
    f32x2 w0a = *(const f32x2*)(W0 + 2*d);
    f32x2 w0b = *(const f32x2*)(W0 + 64 + 2*d);
    f32x2 b0v = *(const f32x2*)(b0 + 2*d);
    f32x2 preA = y2a * w0a + (y3a * w0b + b0v);
    f32x2 preB = y2b * w0a + (y3b * w0b + b0v);
    float a0 = fast_tanh(preA.x), a1 = fast_tanh(preA.y);
    float b0_ = fast_tanh(preB.x), b1 = fast_tanh(preB.y);
    hp0[d] = pack2bf(a0, a1);
    up0[d] = pack2bf(fmaf(-a0, a0, 1.0f), fmaf(-a1, a1, 1.0f));
    hp1[d] = pack2bf(b0_, b1);
    up1[d] = pack2bf(fmaf(-b0_, b0_, 1.0f), fmaf(-b1, b1, 1.0f));
  }

  float qr0[3] = {0,0,0}, Ar0[3] = {0,0,0}, Br0[3] = {0,0,0};
  float qr1[3] = {0,0,0}, Ar1[3] = {0,0,0}, Br1[3] = {0,0,0};
  const int bsw = (colL & 7) << 4;

#pragma unroll 1
  for (int st = 0; st < 8; ++st){
    int zr = 0;
    asm volatile("" : "+v"(zr));   // opaque 0: defeats LICM of bh/wo loads

    // stage: tiles 0-3 = sample A batch, 4-7 = sample B batch
    if (st < 4) stage_tile(sAw, st,     grp, colL, hp0, up0);
    else        stage_tile(sAw, st - 4, grp, colL, hp1, up1);

    // sample-column fragments (B-operand)
    bf16x8 afh[2], afu[2];
#pragma unroll
    for (int kt = 0; kt < 2; ++kt){
      int off = colL*128 + ((kt*64 + grp*16) ^ bsw);
      afh[kt] = *(const bf16x8*)(sAw + off);
      afu[kt] = *(const bf16x8*)(sAw + 2048 + off);
    }

#pragma unroll
    for (int hd = 0; hd < 3; ++hd){
      // early-issue bh/wo for this hd; consumed only in tail below
      f32x4 bh4_0 = *(const f32x4*)(sBH + hd*32 +      grp*4 + zr);
      f32x4 wo4_0 = *(const f32x4*)(sWO + hd*32 +      grp*4 + zr);
      f32x4 bh4_1 = *(const f32x4*)(sBH + hd*32 + 16 + grp*4 + zr);
      f32x4 wo4_1 = *(const f32x4*)(sWO + hd*32 + 16 + grp*4 + zr);
      float aq = 0.0f, aA = 0.0f, aB = 0.0f;
#pragma unroll
      for (int nt = 0; nt < 2; ++nt){
        bf16x8 bW[2], bA[2], bB[2];
#pragma unroll
        for (int kt = 0; kt < 2; ++kt){
          int rbase2 = (hd*96 + nt*16 + colL) * 128;
          int ko = ((kt*64 + grp*16) ^ bsw);
          bW[kt] = *(const bf16x8*)(sBb + rbase2 + ko);
          bA[kt] = *(const bf16x8*)(sBb + rbase2 + 4096 + ko);
          bB[kt] = *(const bf16x8*)(sBb + rbase2 + 8192 + ko);
        }
        f32x4 cAT = {0,0,0,0}, cA2 = {0,0,0,0}, cA3 = {0,0,0,0};
#pragma unroll
        for (int kt = 0; kt < 2; ++kt){
          cAT = __builtin_amdgcn_mfma_f32_16x16x32_bf16(bW[kt], afh[kt], cAT, 0, 0, 0);
          cA2 = __builtin_amdgcn_mfma_f32_16x16x32_bf16(bA[kt], afu[kt], cA2, 0, 0, 0);
          cA3 = __builtin_amdgcn_mfma_f32_16x16x32_bf16(bB[kt], afu[kt], cA3, 0, 0, 0);
        }
        f32x4 bh4 = nt ? bh4_1 : bh4_0;   // nt unrolled -> static select
        f32x4 wo4 = nt ? wo4_1 : wo4_0;
        float t0 = fast_tanh(cAT[0] + bh4[0]);
        float t1 = fast_tanh(cAT[1] + bh4[1]);
        float t2 = fast_tanh(cAT[2] + bh4[2]);
        float t3 = fast_tanh(cAT[3] + bh4[3]);
        aq = fmaf(t0, wo4[0], aq);
        aq = fmaf(t1, wo4[1], aq);
        aq = fmaf(t2, wo4[2], aq);
        aq = fmaf(t3, wo4[3], aq);
        float dt0 = fmaf(-t0, t0, 1.0f);
        float dt1 = fmaf(-t1, t1, 1.0f);
        float dt2 = fmaf(-t2, t2, 1.0f);
        float dt3 = fmaf(-t3, t3, 1.0f);
        aA = fmaf(dt0, cA2[0], aA);
        aA = fmaf(dt1, cA2[1], aA);
        aA = fmaf(dt2, cA2[2], aA);
        aA = fmaf(dt3, cA2[3], aA);
        aB = fmaf(dt0, cA3[0], aB);
        aB = fmaf(dt1, cA3[1], aB);
        aB = fmaf(dt2, cA3[2], aB);
        aB = fmaf(dt3, cA3[3], aB);
      }
      // n spans the 4 lane-groups -> butterfly
      aq += __shfl_xor(aq, 16, 64);  aq += __shfl_xor(aq, 32, 64);
      aA += __shfl_xor(aA, 16, 64);  aA += __shfl_xor(aA, 32, 64);
      aB += __shfl_xor(aB, 16, 64);  aB += __shfl_xor(aB, 32, 64);
      // keep: batch A owns tile grp, batch B owns tile grp+4
      bool k0 = (st == grp);
      bool k1 = (st == grp + 4);
      qr0[hd] = k0 ? aq : qr0[hd];  qr1[hd] = k1 ? aq : qr1[hd];
      Ar0[hd] = k0 ? aA : Ar0[hd];  Ar1[hd] = k1 ? aA : Ar1[hd];
      Br0[hd] = k0 ? aB : Br0[hd];  Br1[hd] = k1 ? aB : Br1[hd];
    }
  }

  q1a = __expf(qr0[0] + bo_v[0]);
  q2a = __expf(qr0[1] + bo_v[1]);
  q3a = __expf(qr0[2] + bo_v[2]);
  s11a = Ar0[0]; s21a = Ar0[1]; s31a = Ar0[2];   // SIG folded into B
  s12a = Br0[0]; s22a = Br0[1]; s32a = Br0[2];
  q1b = __expf(qr1[0] + bo_v[0]);
  q2b = __expf(qr1[1] + bo_v[1]);
  q3b = __expf(qr1[2] + bo_v[2]);
  s11b = Ar1[0]; s21b = Ar1[1]; s31b = Ar1[2];
  s12b = Br1[0]; s22b = Br1[1]; s32b = Br1[2];
}

// NOTE: no min-waves __launch_bounds__ arg — it forces accumulator spills.
__global__ __launch_bounds__(NB)
void sim_kernel(const float* __restrict__ Y,
  const float* __restrict__ W0,  const float* __restrict__ b0,
  const float* __restrict__ Wh1, const float* __restrict__ bh1,
  const float* __restrict__ Wo1, const float* __restrict__ bo1,
  const float* __restrict__ Wh2, const float* __restrict__ bh2,
  const float* __restrict__ Wo2, const float* __restrict__ bo2,
  const float* __restrict__ Wh3, const float* __restrict__ bh3,
  const float* __restrict__ Wo3, const float* __restrict__ bo3,
  float* __restrict__ out, int n)
{
  __shared__ __align__(16) char sB[288 * 128];         // 36 KB
  __shared__ __align__(16) char sA[4][2 * 16 * 128];   // per-wave {h,u} (16 KB)
  __shared__ __align__(16) float sBH[96];
  __shared__ __align__(16) float sWO[96];

  for (int e = threadIdx.x; e < 18432; e += NB){
    int hd   = e / 6144;
    int rem  = e - hd * 6144;
    int mat  = rem >> 11;          // 0=Wh, 1=w0a-scaled, 2=w0b-scaled
    int rem2 = rem & 2047;
    int j = rem2 >> 5, i = rem2 & 31;
    const float* W  = (hd == 0) ? Wh1 : (hd == 1) ? Wh2 : Wh3;
    const float* WO = (hd == 0) ? Wo1 : (hd == 1) ? Wo2 : Wo3;
    float wh = W[j * 32 + i];
    float sc = WO[i] * 0.03f;      // wo * SIGMA fold (JVP mats only)
    float v  = (mat == 0) ? wh
             : (mat == 1) ? W0[j] * wh * sc
                          : W0[64 + j] * wh * sc;
    int R   = hd * 96 + mat * 32 + i;
    int off = (R * 128 + j * 2) ^ ((R & 7) << 4);
    *(unsigned short*)(sB + off) = (unsigned short)f2bfbits(v);
  }
  if (threadIdx.x < 96){
    int hd = threadIdx.x >> 5, row = threadIdx.x & 31;
    const float* BH = (hd == 0) ? bh1 : (hd == 1) ? bh2 : bh3;
    const float* WO = (hd == 0) ? Wo1 : (hd == 1) ? Wo2 : Wo3;
    sBH[threadIdx.x] = BH[row];
    sWO[threadIdx.x] = WO[row];
  }
  __syncthreads();

  const int wv   = threadIdx.x >> 6;
  const int lane = threadIdx.x & 63;
  const int colL = lane & 15;
  const int grp  = lane >> 4;
  char* sAw = &sA[wv][0];

  float bo_v[3] = {bo1[0], bo2[0], bo3[0]};

  // two samples per thread: wave covers 128 consecutive samples
  const int base = blockIdx.x * (2 * NB) + wv * 128;
  const int iiA  = base + lane;
  const int iiB  = base + 64 + lane;
  const int iA   = (iiA < n) ? iiA : (n - 1);
  const int iB   = (iiB < n) ? iiB : (n - 1);
  const float validA = (iiA < n) ? 1.0f : 0.0f;
  const float validB = (iiB < n) ? 1.0f : 0.0f;

  const float2 yvA = ((const float2*)Y)[iA];
  const float2 yvB = ((const float2*)Y)[iB];

  float q1a,q2a,q3a,s11a,s21a,s31a,s12a,s22a,s32a;
  float q1b,q2b,q3b,s11b,s21b,s31b,s12b,s22b,s32b;
  net_eval2(yvA.x, yvA.y, yvB.x, yvB.y, W0, b0, sAw, sB, sBH, sWO,
            colL, grp, bo_v,
            q1a,q2a,q3a,s11a,s21a,s31a,s12a,s22a,s32a,
            q1b,q2b,q3b,s11b,s21b,s31b,s12b,s22b,s32b);
  float Y2a = yvA.x, Y3a = yvA.y;
  float Y2b = yvB.x, Y3b = yvB.y;
  float lossA = 0.0f, lossB = 0.0f;

  for (int t = 0; t < PERIOD; ++t){
    // --- noise (bit-exact threefry rollout), both samples ---
    uint32_t iA0 = 2u * ((uint32_t)t * (uint32_t)n + (uint32_t)iA);
    uint32_t iB0 = 2u * ((uint32_t)t * (uint32_t)n + (uint32_t)iB);
    uint32_t a0,a1,c0,c1,e0,e1,g0,g1;
    threefry2x32_k42(0u, iA0,      a0, a1);
    threefry2x32_k42(0u, iA0 + 1u, c0, c1);
    threefry2x32_k42(0u, iB0,      e0, e1);
    threefry2x32_k42(0u, iB0 + 1u, g0, g1);
    float dZ1a = 0.070710678f * normal_from_bits(a0 ^ a1);
    float dZ2a = 0.070710678f * normal_from_bits(c0 ^ c1);
    float dZ1b = 0.070710678f * normal_from_bits(e0 ^ e1);
    float dZ2b = 0.070710678f * normal_from_bits(g0 ^ g1);

    float q1na,q2na,q3na,Y2na,Y3na;
    float q1nb,q2nb,q3nb,Y2nb,Y3nb;
    step_math(dZ1a, dZ2a, q1a,q2a,q3a,Y2a,Y3a,
              s11a,s21a,s31a,s12a,s22a,s32a, q1na,q2na,q3na,Y2na,Y3na);
    step_math(dZ1b, dZ2b, q1b,q2b,q3b,Y2b,Y3b,
              s11b,s21b,s31b,s12b,s22b,s32b, q1nb,q2nb,q3nb,Y2nb,Y3nb);

    float qt1a,qt2a,qt3a, qt1b,qt2b,qt3b;
    net_eval2(Y2na, Y3na, Y2nb, Y3nb, W0, b0, sAw, sB, sBH, sWO,
              colL, grp, bo_v,
              qt1a,qt2a,qt3a, s11a,s21a,s31a,s12a,s22a,s32a,
              qt1b,qt2b,qt3b, s11b,s21b,s31b,s12b,s22b,s32b);

    float e1a = q1na - qt1a, e2a = q2na - qt2a, e3a = q3na - qt3a;
    float e1b = q1nb - qt1b, e2b = q2nb - qt2b, e3b = q3nb - qt3b;
    lossA += e1a*e1a + e2a*e2a + e3a*e3a;
    lossB += e1b*e1b + e2b*e2b + e3b*e3b;

    q1a = q1na; q2a = q2na; q3a = q3na; Y2a = Y2na; Y3a = Y3na;
    q1b = q1nb; q2b = q2nb; q3b = q3nb; Y2b = Y2nb; Y3b = Y3nb;
  }

  float loss = (lossA * validA + lossB * validB) * (1.0f / ((float)15000000));

  // --- block reduction -> one atomic per block ---
#pragma unroll
  for (int off = 32; off > 0; off >>= 1)
    loss += __shfl_down(loss, off, 64);
  __shared__ float sred[NB / 64];
  if (lane == 0) sred[wv] = loss;
  __syncthreads();
  if (threadIdx.x == 0){
    float s = 0.0f;
#pragma unroll
    for (int w = 0; w < NB / 64; ++w) s += sred[w];
    atomicAdd(out, s);
  }
}

extern "C" void kernel_launch(void* const* d_in, const int* in_sizes, int n_in,
                              void* d_out, int out_size, void* d_ws, size_t ws_size,
                              hipStream_t stream)
{
  const float* Y   = (const float*)d_in[0];
  const float* W0  = (const float*)d_in[1];
  const float* b0  = (const float*)d_in[2];
  const float* Wh1 = (const float*)d_in[3];
  const float* bh1 = (const float*)d_in[4];
  const float* Wo1 = (const float*)d_in[5];
  const float* bo1 = (const float*)d_in[6];
  const float* Wh2 = (const float*)d_in[7];
  const float* bh2 = (const float*)d_in[8];
  const float* Wo2 = (const float*)d_in[9];
  const float* bo2 = (const float*)d_in[10];
  const float* Wh3 = (const float*)d_in[11];
  const float* bh3 = (const float*)d_in[12];
  const float* Wo3 = (const float*)d_in[13];
  const float* bo3 = (const float*)d_in[14];

  const int n = in_sizes[0] / 2;

  (void)hipMemsetAsync(d_out, 0, sizeof(float), stream);

  const int grid = (n + 2*NB - 1) / (2*NB);
  sim_kernel<<<grid, NB, 0, stream>>>(Y,
      W0, b0, Wh1, bh1, Wo1, bo1, Wh2, bh2, Wo2, bo2, Wh3, bh3, Wo3, bo3,
      (float*)d_out, n);
}

// Round 18
// 2332.707 us; speedup vs baseline: 1.1090x; 1.1090x over previous
//
#include <hip/hip_runtime.h>
#include <hip/hip_bf16.h>
#include <stdint.h>

#define NB 256
#define PERIOD 30

typedef __bf16  bf16x8 __attribute__((ext_vector_type(8)));
typedef float   f32x4  __attribute__((ext_vector_type(4)));
typedef float   f32x2  __attribute__((ext_vector_type(2)));
typedef unsigned int uint4v __attribute__((ext_vector_type(4)));

__device__ __forceinline__ float frcp(float x){ return __builtin_amdgcn_rcpf(x); }

// tanh(x) = 1 - 2/(exp(2x)+1)  (argument in natural domain)
__device__ __forceinline__ float fast_tanh(float x){
  float e = __expf(2.0f*x);
  return fmaf(-2.0f, frcp(e + 1.0f), 1.0f);
}

// tanh with PRE-SCALED argument: xs = (2*log2 e) * x  ->  no mul needed
__device__ __forceinline__ float fast_tanh_pre(float xs){
  float e = exp2f(xs);                       // v_exp_f32 directly
  return fmaf(-2.0f, frcp(e + 1.0f), 1.0f);
}

__device__ __forceinline__ unsigned int f2bfbits(float x){
  union { __hip_bfloat16 b; unsigned short u; } v;
  v.b = __float2bfloat16(x);          // RNE, matches XLA convert
  return (unsigned int)v.u;
}
__device__ __forceinline__ unsigned int pack2bf(float lo, float hi){
  return f2bfbits(lo) | (f2bfbits(hi) << 16);
}

// Threefry-2x32, 20 rounds, key = (0, 42)
__device__ __forceinline__ void threefry2x32_k42(uint32_t x0, uint32_t x1,
                                                 uint32_t& o0, uint32_t& o1){
  const uint32_t ks0 = 0u, ks1 = 42u, ks2 = 0u ^ 42u ^ 0x1BD11BDAu;
  x0 += ks0; x1 += ks1;
#define TFR(rot) { x0 += x1; x1 = (x1 << (rot)) | (x1 >> (32 - (rot))); x1 ^= x0; }
  TFR(13) TFR(15) TFR(26) TFR(6)
  x0 += ks1; x1 += ks2 + 1u;
  TFR(17) TFR(29) TFR(16) TFR(24)
  x0 += ks2; x1 += ks0 + 2u;
  TFR(13) TFR(15) TFR(26) TFR(6)
  x0 += ks0; x1 += ks1 + 3u;
  TFR(17) TFR(29) TFR(16) TFR(24)
  x0 += ks1; x1 += ks2 + 4u;
  TFR(13) TFR(15) TFR(26) TFR(6)
  x0 += ks2; x1 += ks0 + 5u;
#undef TFR
  o0 = x0; o1 = x1;
}

// Mirror jax.random.normal f32 (XLA erfinv polynomial)
__device__ __forceinline__ float normal_from_bits(uint32_t bits){
  float f = __uint_as_float((bits >> 9) | 0x3f800000u) - 1.0f;
  const float lo = -0.99999994f;
  float u = fmaf(f, 2.0f, lo);
  u = fmaxf(u, lo);
  float w = -log1pf(-u*u);
  float p;
  if (w < 5.0f){
    float ww = w - 2.5f;
    p = 2.81022636e-08f;
    p = fmaf(p, ww, 3.43273939e-07f);
    p = fmaf(p, ww, -3.5233877e-06f);
    p = fmaf(p, ww, -4.39150654e-06f);
    p = fmaf(p, ww, 0.00021858087f);
    p = fmaf(p, ww, -0.00125372503f);
    p = fmaf(p, ww, -0.00417768164f);
    p = fmaf(p, ww, 0.246640727f);
    p = fmaf(p, ww, 1.50140941f);
  } else {
    float ww = sqrtf(w) - 3.0f;
    p = -0.000200214257f;
    p = fmaf(p, ww, 0.000100950558f);
    p = fmaf(p, ww, 0.00134934322f);
    p = fmaf(p, ww, -0.00367342844f);
    p = fmaf(p, ww, 0.00573950773f);
    p = fmaf(p, ww, -0.0076224613f);
    p = fmaf(p, ww, 0.00943887047f);
    p = fmaf(p, ww, 1.00167406f);
    p = fmaf(p, ww, 2.83297682f);
  }
  return 1.41421356f * (p * u);
}

// stage one sample-tile's h/u rows (owners = lanes with grp==st)
__device__ __forceinline__ void stage_tile(char* buf, int st, int grp, int colL,
    const unsigned int* hp, const unsigned int* up){
  if (grp == st){
    const int rbase = colL * 128;
    const int sw = (colL & 7) << 4;
#pragma unroll
    for (int w = 0; w < 8; ++w){
      int off = rbase + ((w * 16) ^ sw);
      *(uint4v*)(buf + off)        = uint4v{hp[w*4], hp[w*4+1], hp[w*4+2], hp[w*4+3]};
      *(uint4v*)(buf + 2048 + off) = uint4v{up[w*4], up[w*4+1], up[w*4+2], up[w*4+3]};
    }
  }
}

// MFMA net eval, C[n, sample] orientation — EXACT R15 structure (best: 2207us).
// Init-time folds (free at runtime):
//   mat0 = (2 log2 e)·Wh^T, sBH = (2 log2 e)·bh  -> tail tanh needs NO mul
//   sWO = (log2 e)·wo, bo_v = (log2 e)·bo        -> final exp is exp2f, no mul
//   mat1/2 = (diag(w0*) Wh diag(wo·SIG))^T        -> s-values emerge scaled
// bh folded via MFMA C-seed (R15-proven; bh/wo loads left LICM-able — R16/17
// showed forcing per-iteration reloads costs more than the 48 regs).
__device__ __forceinline__ void net_eval(
    float y2, float y3,
    const float* __restrict__ W0, const float* __restrict__ b0,
    char* sAw,                        // this wave's A buffer: [2][16][128B]
    const char* __restrict__ sBb,     // B matrices [3hd][3mat][32n][128B]
    const float* __restrict__ sBH,    // [3][32] f32 bh * 2log2e
    const float* __restrict__ sWO,    // [3][32] f32 wo * log2e
    int colL, int grp,
    const float* bo_v,                // bo * log2e
    float& q1o, float& q2o, float& q3o,
    float& s11, float& s21, float& s31,
    float& s12, float& s22, float& s32)
{
  // ---- first layer (f32x2 pairs, per-lane = per-sample): h and u packs ----
  unsigned int hp[32], up[32];
#pragma unroll
  for (int d = 0; d < 32; ++d){
    f32x2 w0a = *(const f32x2*)(W0 + 2*d);
    f32x2 w0b = *(const f32x2*)(W0 + 64 + 2*d);
    f32x2 b0v = *(const f32x2*)(b0 + 2*d);
    f32x2 pre = y2 * w0a + (y3 * w0b + b0v);      // v_pk_fma_f32 x2
    float hA = fast_tanh(pre.x), hB = fast_tanh(pre.y);
    f32x2 h  = {hA, hB};
    f32x2 u  = 1.0f - h * h;
    hp[d] = pack2bf(hA, hB);
    up[d] = pack2bf(u.x, u.y);
  }

  float qraw[3] = {0,0,0}, Araw[3] = {0,0,0}, Braw[3] = {0,0,0};
  const int bsw = (colL & 7) << 4;

#pragma unroll 1
  for (int st = 0; st < 4; ++st){
    // stage this tile in-place (same-wave program order -> overwrite safe)
    stage_tile(sAw, st, grp, colL, hp, up);

    // sample-column fragments for this tile (B-operand)
    bf16x8 afh[2], afu[2];
#pragma unroll
    for (int kt = 0; kt < 2; ++kt){
      int off = colL*128 + ((kt*64 + grp*16) ^ bsw);
      afh[kt] = *(const bf16x8*)(sAw + off);
      afu[kt] = *(const bf16x8*)(sAw + 2048 + off);
    }

#pragma unroll
    for (int hd = 0; hd < 3; ++hd){
      float aq = 0.0f, aA = 0.0f, aB = 0.0f;
#pragma unroll
      for (int nt = 0; nt < 2; ++nt){
        // B-matrix fragments (A-operand) from LDS at point of use
        bf16x8 bW[2], bA[2], bB[2];
#pragma unroll
        for (int kt = 0; kt < 2; ++kt){
          int rbase2 = (hd*96 + nt*16 + colL) * 128;
          int ko = ((kt*64 + grp*16) ^ bsw);
          bW[kt] = *(const bf16x8*)(sBb + rbase2 + ko);
          bA[kt] = *(const bf16x8*)(sBb + rbase2 + 4096 + ko);
          bB[kt] = *(const bf16x8*)(sBb + rbase2 + 8192 + ko);
        }
        // this lane's 4 n-rows: n = nt*16 + grp*4 + r
        f32x4 bh4 = *(const f32x4*)(sBH + hd*32 + nt*16 + grp*4);
        f32x4 wo4 = *(const f32x4*)(sWO + hd*32 + nt*16 + grp*4);
        f32x4 cAT = bh4;                     // (2log2e)-scaled bh via C-seed
        f32x4 cA2 = {0,0,0,0}, cA3 = {0,0,0,0};
#pragma unroll
        for (int kt = 0; kt < 2; ++kt){
          cAT = __builtin_amdgcn_mfma_f32_16x16x32_bf16(bW[kt], afh[kt], cAT, 0, 0, 0);
          cA2 = __builtin_amdgcn_mfma_f32_16x16x32_bf16(bA[kt], afu[kt], cA2, 0, 0, 0);
          cA3 = __builtin_amdgcn_mfma_f32_16x16x32_bf16(bB[kt], afu[kt], cA3, 0, 0, 0);
        }
        float t0 = fast_tanh_pre(cAT[0]);    // arg already exp2-domain
        float t1 = fast_tanh_pre(cAT[1]);
        float t2 = fast_tanh_pre(cAT[2]);
        float t3 = fast_tanh_pre(cAT[3]);
        // q-path: wo (log2e-scaled) in f32
        aq = fmaf(t0, wo4[0], aq);
        aq = fmaf(t1, wo4[1], aq);
        aq = fmaf(t2, wo4[2], aq);
        aq = fmaf(t3, wo4[3], aq);
        // JVP paths: wo*SIG pre-folded into the B matrices
        float dt0 = fmaf(-t0, t0, 1.0f);
        float dt1 = fmaf(-t1, t1, 1.0f);
        float dt2 = fmaf(-t2, t2, 1.0f);
        float dt3 = fmaf(-t3, t3, 1.0f);
        aA = fmaf(dt0, cA2[0], aA);
        aA = fmaf(dt1, cA2[1], aA);
        aA = fmaf(dt2, cA2[2], aA);
        aA = fmaf(dt3, cA2[3], aA);
        aB = fmaf(dt0, cA3[0], aB);
        aB = fmaf(dt1, cA3[1], aB);
        aB = fmaf(dt2, cA3[2], aB);
        aB = fmaf(dt3, cA3[3], aB);
      }
      // cross-group reduce: n also spans the 4 lane-groups
      aq += __shfl_xor(aq, 16, 64);  aq += __shfl_xor(aq, 32, 64);
      aA += __shfl_xor(aA, 16, 64);  aA += __shfl_xor(aA, 32, 64);
      aB += __shfl_xor(aB, 16, 64);  aB += __shfl_xor(aB, 32, 64);
      // after butterfly every lane holds sample (st*16+colL)'s sum;
      // lane owns sample (grp*16+colL) -> keep when st == grp
      bool keep = (st == grp);
      qraw[hd] = keep ? aq : qraw[hd];
      Araw[hd] = keep ? aA : Araw[hd];
      Braw[hd] = keep ? aB : Braw[hd];
    }
  }

  q1o = exp2f(qraw[0] + bo_v[0]);    // wo,bo log2e-scaled -> exp2, no mul
  q2o = exp2f(qraw[1] + bo_v[1]);
  q3o = exp2f(qraw[2] + bo_v[2]);
  s11 = Araw[0]; s21 = Araw[1]; s31 = Araw[2];   // SIG folded into B
  s12 = Braw[0]; s22 = Braw[1]; s32 = Braw[2];
}

// NOTE: no min-waves __launch_bounds__ arg — it forces accumulator spills
// ((256,3)->210GB, (256,4)->42GB scratch writes). Natural allocation is clean.
__global__ __launch_bounds__(NB)
void sim_kernel(const float* __restrict__ Y,
  const float* __restrict__ W0,  const float* __restrict__ b0,
  const float* __restrict__ Wh1, const float* __restrict__ bh1,
  const float* __restrict__ Wo1, const float* __restrict__ bo1,
  const float* __restrict__ Wh2, const float* __restrict__ bh2,
  const float* __restrict__ Wo2, const float* __restrict__ bo2,
  const float* __restrict__ Wh3, const float* __restrict__ bh3,
  const float* __restrict__ Wo3, const float* __restrict__ bo3,
  float* __restrict__ out, int n)
{
  // B matrices: per head {(2log2e)·Wh^T, (diag(w0a)Wh diag(wo*SIG))^T,
  // (diag(w0b)Wh diag(wo*SIG))^T}, bf16, swizzled 128B rows. 288 rows = 36 KB.
  __shared__ __align__(16) char sB[288 * 128];
  __shared__ __align__(16) char sA[4][2 * 16 * 128];   // per-wave {h,u} (16 KB)
  __shared__ __align__(16) float sBH[96];              // bh * 2log2e
  __shared__ __align__(16) float sWO[96];              // wo * log2e

  const float K2L = 2.8853900817779268f;   // 2*log2(e)
  const float L2E = 1.4426950408889634f;   // log2(e)

  for (int e = threadIdx.x; e < 18432; e += NB){
    int hd   = e / 6144;
    int rem  = e - hd * 6144;
    int mat  = rem >> 11;          // 0=Wh(k-scaled), 1=w0a-scaled, 2=w0b-scaled
    int rem2 = rem & 2047;
    int j = rem2 >> 5, i = rem2 & 31;
    const float* W  = (hd == 0) ? Wh1 : (hd == 1) ? Wh2 : Wh3;
    const float* WO = (hd == 0) ? Wo1 : (hd == 1) ? Wo2 : Wo3;
    float wh = W[j * 32 + i];
    float sc = WO[i] * 0.03f;      // wo * SIGMA fold (JVP mats only)
    float v  = (mat == 0) ? K2L * wh
             : (mat == 1) ? W0[j] * wh * sc
                          : W0[64 + j] * wh * sc;
    int R   = hd * 96 + mat * 32 + i;
    int off = (R * 128 + j * 2) ^ ((R & 7) << 4);
    *(unsigned short*)(sB + off) = (unsigned short)f2bfbits(v);
  }
  if (threadIdx.x < 96){
    int hd = threadIdx.x >> 5, row = threadIdx.x & 31;
    const float* BH = (hd == 0) ? bh1 : (hd == 1) ? bh2 : bh3;
    const float* WO = (hd == 0) ? Wo1 : (hd == 1) ? Wo2 : Wo3;
    sBH[threadIdx.x] = K2L * BH[row];
    sWO[threadIdx.x] = L2E * WO[row];
  }
  __syncthreads();

  const int wv   = threadIdx.x >> 6;
  const int lane = threadIdx.x & 63;
  const int colL = lane & 15;
  const int grp  = lane >> 4;
  char* sAw = &sA[wv][0];

  float bo_v[3] = {L2E * bo1[0], L2E * bo2[0], L2E * bo3[0]};

  const int gid = blockIdx.x * NB + threadIdx.x;
  const int ii  = (gid < n) ? gid : (n - 1);
  const float valid = (gid < n) ? 1.0f : 0.0f;

  const float2 yv = ((const float2*)Y)[ii];
  const float y2 = yv.x, y3 = yv.y;

  const float GAMMA = 1.2f, DT = 0.005f, SIGMA = 0.03f;
  const float KAPPA = 0.2f, YBAR = 2.0f, RHO = 0.03f, Bc = 1.0f, Cc = 0.1f;

  float q1,q2,q3,s11,s21,s31,s12,s22,s32;
  net_eval(y2, y3, W0, b0, sAw, sB, sBH, sWO, colL, grp, bo_v,
           q1,q2,q3,s11,s21,s31,s12,s22,s32);
  float Y2 = y2, Y3 = y3;
  float loss = 0.0f;

  for (int t = 0; t < PERIOD; ++t){
    // --- noise: threefry rollout, counter = flat index (bit-exact) ---
    uint32_t idx0 = 2u * ((uint32_t)t * (uint32_t)n + (uint32_t)ii);
    uint32_t a0, a1, c0, c1;
    threefry2x32_k42(0u, idx0,      a0, a1);
    threefry2x32_k42(0u, idx0 + 1u, c0, c1);
    float dZ1 = 0.070710678f * normal_from_bits(a0 ^ a1);
    float dZ2 = 0.070710678f * normal_from_bits(c0 ^ c1);

    // --- step math (mirror reference, f32) ---
    float Wt  = q1 + q2 + q3;
    float q1h = q1 / Wt;
    float q2h = q2 / Wt;
    float q3h = 1.0f - q1h - q2h;
    float q1sq = q1 * q1;
    float c   = Bc*q1 - Cc*q1sq + Y2 + Y3;
    float bq  = Bc*q1 - 2.0f*Cc*q1sq;
    float sc1 = fmaf(bq, s11, SIGMA);
    float sc2 = fmaf(bq, s12, SIGMA);
    float sW1 = q1*s11 + q2*s21 + q3*s31;
    float sW2 = q1*s12 + q2*s22 + q3*s32;
    float sJ1 = 6.0f * (sc1/c - sW1/Wt);
    float sJ2 = 6.0f * (sc2/c - sW2/Wt);
    float d11 = s11*s11 + s12*s12;
    float d12 = s11*s21 + s12*s22;
    float d13 = s11*s31 + s12*s32;
    float d22 = s21*s21 + s22*s22;
    float d23 = s21*s31 + s22*s32;
    float d33 = s31*s31 + s32*s32;
    const float oneMG = 1.0f - GAMMA;   // -0.2
    float p1 = GAMMA*(q1h*d11 + q2h*d12 + q3h*d13) - oneMG*(sJ1*s11 + sJ2*s12);
    float p2 = GAMMA*(q1h*d12 + q2h*d22 + q3h*d23) - oneMG*(sJ1*s21 + sJ2*s22);
    float p3 = GAMMA*(q1h*d13 + q2h*d23 + q3h*d33) - oneMG*(sJ1*s31 + sJ2*s32);
    float muY2 = KAPPA * (YBAR - Y2);
    float muY3 = KAPPA * (YBAR - Y3);
    float r = RHO + GAMMA*(bq*(p1 - (Bc - Cc*q1)) - Cc*q1sq*d11 + muY2 + muY3)/c
                  - 1.32f*(sc1*sc1 + sc2*sc2)/(c*c);
    r = r / (1.0f - GAMMA*bq/c);
    float mu1 = r + p1 - (Bc - Cc*q1);
    float mu2 = r + p2 - Y2/q2;
    float mu3 = r + p3 - Y3/q3;
    float q1n = q1 * (1.0f + mu1*DT + s11*dZ1 + s12*dZ2);
    float q2n = q2 * (1.0f + mu2*DT + s21*dZ1 + s22*dZ2);
    float q3n = q3 * (1.0f + mu3*DT + s31*dZ1 + s32*dZ2);
    float Y2n = Y2 + muY2*DT + SIGMA*dZ1;
    float Y3n = Y3 + muY3*DT + SIGMA*dZ2;

    float qt1, qt2, qt3;
    net_eval(Y2n, Y3n, W0, b0, sAw, sB, sBH, sWO, colL, grp, bo_v,
             qt1,qt2,qt3, s11,s21,s31,s12,s22,s32);

    float e1 = q1n - qt1, e2 = q2n - qt2, e3 = q3n - qt3;
    loss += e1*e1 + e2*e2 + e3*e3;

    q1 = q1n; q2 = q2n; q3 = q3n; Y2 = Y2n; Y3 = Y3n;
  }

  loss *= valid * (1.0f / ((float)15000000));   // / (n * PERIOD)

  // --- block reduction -> one atomic per block ---
#pragma unroll
  for (int off = 32; off > 0; off >>= 1)
    loss += __shfl_down(loss, off, 64);
  __shared__ float sred[NB / 64];
  if (lane == 0) sred[wv] = loss;
  __syncthreads();
  if (threadIdx.x == 0){
    float s = 0.0f;
#pragma unroll
    for (int w = 0; w < NB / 64; ++w) s += sred[w];
    atomicAdd(out, s);
  }
}

extern "C" void kernel_launch(void* const* d_in, const int* in_sizes, int n_in,
                              void* d_out, int out_size, void* d_ws, size_t ws_size,
                              hipStream_t stream)
{
  const float* Y   = (const float*)d_in[0];
  const float* W0  = (const float*)d_in[1];
  const float* b0  = (const float*)d_in[2];
  const float* Wh1 = (const float*)d_in[3];
  const float* bh1 = (const float*)d_in[4];
  const float* Wo1 = (const float*)d_in[5];
  const float* bo1 = (const float*)d_in[6];
  const float* Wh2 = (const float*)d_in[7];
  const float* bh2 = (const float*)d_in[8];
  const float* Wo2 = (const float*)d_in[9];
  const float* bo2 = (const float*)d_in[10];
  const float* Wh3 = (const float*)d_in[11];
  const float* bh3 = (const float*)d_in[12];
  const float* Wo3 = (const float*)d_in[13];
  const float* bo3 = (const float*)d_in[14];

  const int n = in_sizes[0] / 2;

  (void)hipMemsetAsync(d_out, 0, sizeof(float), stream);

  const int grid = (n + NB - 1) / NB;
  sim_kernel<<<grid, NB, 0, stream>>>(Y,
      W0, b0, Wh1, bh1, Wo1, bo1, Wh2, bh2, Wo2, bo2, Wh3, bh3, Wo3, bo3,
      (float*)d_out, n);
}

// Round 19
// 2206.305 us; speedup vs baseline: 1.1726x; 1.0573x over previous
//
#include <hip/hip_runtime.h>
#include <hip/hip_bf16.h>
#include <stdint.h>

#define NB 256
#define PERIOD 30

typedef __bf16  bf16x8 __attribute__((ext_vector_type(8)));
typedef float   f32x4  __attribute__((ext_vector_type(4)));
typedef float   f32x2  __attribute__((ext_vector_type(2)));
typedef unsigned int uint4v __attribute__((ext_vector_type(4)));

__device__ __forceinline__ float frcp(float x){ return __builtin_amdgcn_rcpf(x); }

// tanh(x) = 1 - 2/(exp(2x)+1)
__device__ __forceinline__ float fast_tanh(float x){
  float e = __expf(2.0f*x);
  return fmaf(-2.0f, frcp(e + 1.0f), 1.0f);
}

__device__ __forceinline__ unsigned int f2bfbits(float x){
  union { __hip_bfloat16 b; unsigned short u; } v;
  v.b = __float2bfloat16(x);          // RNE, matches XLA convert
  return (unsigned int)v.u;
}
__device__ __forceinline__ unsigned int pack2bf(float lo, float hi){
  return f2bfbits(lo) | (f2bfbits(hi) << 16);
}

// Threefry-2x32, 20 rounds, key = (0, 42)
__device__ __forceinline__ void threefry2x32_k42(uint32_t x0, uint32_t x1,
                                                 uint32_t& o0, uint32_t& o1){
  const uint32_t ks0 = 0u, ks1 = 42u, ks2 = 0u ^ 42u ^ 0x1BD11BDAu;
  x0 += ks0; x1 += ks1;
#define TFR(rot) { x0 += x1; x1 = (x1 << (rot)) | (x1 >> (32 - (rot))); x1 ^= x0; }
  TFR(13) TFR(15) TFR(26) TFR(6)
  x0 += ks1; x1 += ks2 + 1u;
  TFR(17) TFR(29) TFR(16) TFR(24)
  x0 += ks2; x1 += ks0 + 2u;
  TFR(13) TFR(15) TFR(26) TFR(6)
  x0 += ks0; x1 += ks1 + 3u;
  TFR(17) TFR(29) TFR(16) TFR(24)
  x0 += ks1; x1 += ks2 + 4u;
  TFR(13) TFR(15) TFR(26) TFR(6)
  x0 += ks2; x1 += ks0 + 5u;
#undef TFR
  o0 = x0; o1 = x1;
}

// Mirror jax.random.normal f32 (XLA erfinv polynomial)
__device__ __forceinline__ float normal_from_bits(uint32_t bits){
  float f = __uint_as_float((bits >> 9) | 0x3f800000u) - 1.0f;
  const float lo = -0.99999994f;
  float u = fmaf(f, 2.0f, lo);
  u = fmaxf(u, lo);
  float w = -log1pf(-u*u);
  float p;
  if (w < 5.0f){
    float ww = w - 2.5f;
    p = 2.81022636e-08f;
    p = fmaf(p, ww, 3.43273939e-07f);
    p = fmaf(p, ww, -3.5233877e-06f);
    p = fmaf(p, ww, -4.39150654e-06f);
    p = fmaf(p, ww, 0.00021858087f);
    p = fmaf(p, ww, -0.00125372503f);
    p = fmaf(p, ww, -0.00417768164f);
    p = fmaf(p, ww, 0.246640727f);
    p = fmaf(p, ww, 1.50140941f);
  } else {
    float ww = sqrtf(w) - 3.0f;
    p = -0.000200214257f;
    p = fmaf(p, ww, 0.000100950558f);
    p = fmaf(p, ww, 0.00134934322f);
    p = fmaf(p, ww, -0.00367342844f);
    p = fmaf(p, ww, 0.00573950773f);
    p = fmaf(p, ww, -0.0076224613f);
    p = fmaf(p, ww, 0.00943887047f);
    p = fmaf(p, ww, 1.00167406f);
    p = fmaf(p, ww, 2.83297682f);
  }
  return 1.41421356f * (p * u);
}

// stage one sample-tile's h/u rows (owners = lanes with grp==st)
__device__ __forceinline__ void stage_tile(char* buf, int st, int grp, int colL,
    const unsigned int* hp, const unsigned int* up){
  if (grp == st){
    const int rbase = colL * 128;
    const int sw = (colL & 7) << 4;
#pragma unroll
    for (int w = 0; w < 8; ++w){
      int off = rbase + ((w * 16) ^ sw);
      *(uint4v*)(buf + off)        = uint4v{hp[w*4], hp[w*4+1], hp[w*4+2], hp[w*4+3]};
      *(uint4v*)(buf + 2048 + off) = uint4v{up[w*4], up[w*4+1], up[w*4+2], up[w*4+3]};
    }
  }
}

// MFMA net eval, C[n, sample] orientation (R15 — session best, 2207us).
// A-operand = B-matrix rows (n), B-operand = staged h/u sample columns.
// n-reduction is in-lane over r/nt + 2 shfl_xor(16,32); bh folded via MFMA
// C-seed; bh/wo loads left LICM-able (R16/R17 showed forcing per-iteration
// reloads or 2-sample ILP both regress). wo*SIG folded into JVP matrices.
__device__ __forceinline__ void net_eval(
    float y2, float y3,
    const float* __restrict__ W0, const float* __restrict__ b0,
    char* sAw,                        // this wave's A buffer: [2][16][128B]
    const char* __restrict__ sBb,     // B matrices [3hd][3mat][32n][128B]
    const float* __restrict__ sBH,    // [3][32] f32 bh
    const float* __restrict__ sWO,    // [3][32] f32 wo
    int colL, int grp,
    const float* bo_v,
    float& q1o, float& q2o, float& q3o,
    float& s11, float& s21, float& s31,
    float& s12, float& s22, float& s32)
{
  // ---- first layer (f32x2 pairs, per-lane = per-sample): h and u packs ----
  unsigned int hp[32], up[32];
#pragma unroll
  for (int d = 0; d < 32; ++d){
    f32x2 w0a = *(const f32x2*)(W0 + 2*d);
    f32x2 w0b = *(const f32x2*)(W0 + 64 + 2*d);
    f32x2 b0v = *(const f32x2*)(b0 + 2*d);
    f32x2 pre = y2 * w0a + (y3 * w0b + b0v);      // v_pk_fma_f32 x2
    float hA = fast_tanh(pre.x), hB = fast_tanh(pre.y);
    f32x2 h  = {hA, hB};
    f32x2 u  = 1.0f - h * h;
    hp[d] = pack2bf(hA, hB);
    up[d] = pack2bf(u.x, u.y);
  }

  float qraw[3] = {0,0,0}, Araw[3] = {0,0,0}, Braw[3] = {0,0,0};
  const int bsw = (colL & 7) << 4;

#pragma unroll 1
  for (int st = 0; st < 4; ++st){
    // stage this tile in-place (same-wave program order -> overwrite safe)
    stage_tile(sAw, st, grp, colL, hp, up);

    // sample-column fragments for this tile (B-operand)
    bf16x8 afh[2], afu[2];
#pragma unroll
    for (int kt = 0; kt < 2; ++kt){
      int off = colL*128 + ((kt*64 + grp*16) ^ bsw);
      afh[kt] = *(const bf16x8*)(sAw + off);
      afu[kt] = *(const bf16x8*)(sAw + 2048 + off);
    }

#pragma unroll
    for (int hd = 0; hd < 3; ++hd){
      float aq = 0.0f, aA = 0.0f, aB = 0.0f;
#pragma unroll
      for (int nt = 0; nt < 2; ++nt){
        // B-matrix fragments (A-operand) from LDS at point of use
        bf16x8 bW[2], bA[2], bB[2];
#pragma unroll
        for (int kt = 0; kt < 2; ++kt){
          int rbase2 = (hd*96 + nt*16 + colL) * 128;
          int ko = ((kt*64 + grp*16) ^ bsw);
          bW[kt] = *(const bf16x8*)(sBb + rbase2 + ko);
          bA[kt] = *(const bf16x8*)(sBb + rbase2 + 4096 + ko);
          bB[kt] = *(const bf16x8*)(sBb + rbase2 + 8192 + ko);
        }
        // this lane's 4 n-rows: n = nt*16 + grp*4 + r
        f32x4 bh4 = *(const f32x4*)(sBH + hd*32 + nt*16 + grp*4);
        f32x4 wo4 = *(const f32x4*)(sWO + hd*32 + nt*16 + grp*4);
        f32x4 cAT = bh4;                     // bh folded in via C-seed
        f32x4 cA2 = {0,0,0,0}, cA3 = {0,0,0,0};
#pragma unroll
        for (int kt = 0; kt < 2; ++kt){
          cAT = __builtin_amdgcn_mfma_f32_16x16x32_bf16(bW[kt], afh[kt], cAT, 0, 0, 0);
          cA2 = __builtin_amdgcn_mfma_f32_16x16x32_bf16(bA[kt], afu[kt], cA2, 0, 0, 0);
          cA3 = __builtin_amdgcn_mfma_f32_16x16x32_bf16(bB[kt], afu[kt], cA3, 0, 0, 0);
        }
        float t0 = fast_tanh(cAT[0]);
        float t1 = fast_tanh(cAT[1]);
        float t2 = fast_tanh(cAT[2]);
        float t3 = fast_tanh(cAT[3]);
        // q-path: wo in f32 (tanh blocks folding)
        aq = fmaf(t0, wo4[0], aq);
        aq = fmaf(t1, wo4[1], aq);
        aq = fmaf(t2, wo4[2], aq);
        aq = fmaf(t3, wo4[3], aq);
        // JVP paths: wo*SIG pre-folded into the B matrices
        float dt0 = fmaf(-t0, t0, 1.0f);
        float dt1 = fmaf(-t1, t1, 1.0f);
        float dt2 = fmaf(-t2, t2, 1.0f);
        float dt3 = fmaf(-t3, t3, 1.0f);
        aA = fmaf(dt0, cA2[0], aA);
        aA = fmaf(dt1, cA2[1], aA);
        aA = fmaf(dt2, cA2[2], aA);
        aA = fmaf(dt3, cA2[3], aA);
        aB = fmaf(dt0, cA3[0], aB);
        aB = fmaf(dt1, cA3[1], aB);
        aB = fmaf(dt2, cA3[2], aB);
        aB = fmaf(dt3, cA3[3], aB);
      }
      // cross-group reduce: n also spans the 4 lane-groups
      aq += __shfl_xor(aq, 16, 64);  aq += __shfl_xor(aq, 32, 64);
      aA += __shfl_xor(aA, 16, 64);  aA += __shfl_xor(aA, 32, 64);
      aB += __shfl_xor(aB, 16, 64);  aB += __shfl_xor(aB, 32, 64);
      // after butterfly every lane holds sample (st*16+colL)'s sum;
      // lane owns sample (grp*16+colL) -> keep when st == grp
      bool keep = (st == grp);
      qraw[hd] = keep ? aq : qraw[hd];
      Araw[hd] = keep ? aA : Araw[hd];
      Braw[hd] = keep ? aB : Braw[hd];
    }
  }

  q1o = __expf(qraw[0] + bo_v[0]);
  q2o = __expf(qraw[1] + bo_v[1]);
  q3o = __expf(qraw[2] + bo_v[2]);
  s11 = Araw[0]; s21 = Araw[1]; s31 = Araw[2];   // SIG folded into B
  s12 = Braw[0]; s22 = Braw[1]; s32 = Braw[2];
}

// NOTE: no min-waves __launch_bounds__ arg — it forces accumulator spills
// ((256,3)->210GB, (256,4)->42GB scratch writes). Natural allocation is clean.
__global__ __launch_bounds__(NB)
void sim_kernel(const float* __restrict__ Y,
  const float* __restrict__ W0,  const float* __restrict__ b0,
  const float* __restrict__ Wh1, const float* __restrict__ bh1,
  const float* __restrict__ Wo1, const float* __restrict__ bo1,
  const float* __restrict__ Wh2, const float* __restrict__ bh2,
  const float* __restrict__ Wo2, const float* __restrict__ bo2,
  const float* __restrict__ Wh3, const float* __restrict__ bh3,
  const float* __restrict__ Wo3, const float* __restrict__ bo3,
  float* __restrict__ out, int n)
{
  // B matrices: per head {Wh^T, (diag(w0a)Wh diag(wo*SIG))^T,
  // (diag(w0b)Wh diag(wo*SIG))^T}, bf16, swizzled 128B rows. 288 rows = 36 KB.
  __shared__ __align__(16) char sB[288 * 128];
  __shared__ __align__(16) char sA[4][2 * 16 * 128];   // per-wave {h,u} (16 KB)
  __shared__ __align__(16) float sBH[96];              // bh per head/n (f32)
  __shared__ __align__(16) float sWO[96];              // wo per head/n (f32)

  for (int e = threadIdx.x; e < 18432; e += NB){
    int hd   = e / 6144;
    int rem  = e - hd * 6144;
    int mat  = rem >> 11;          // 0=Wh, 1=w0a-scaled, 2=w0b-scaled
    int rem2 = rem & 2047;
    int j = rem2 >> 5, i = rem2 & 31;
    const float* W  = (hd == 0) ? Wh1 : (hd == 1) ? Wh2 : Wh3;
    const float* WO = (hd == 0) ? Wo1 : (hd == 1) ? Wo2 : Wo3;
    float wh = W[j * 32 + i];
    float sc = WO[i] * 0.03f;      // wo * SIGMA fold (JVP mats only)
    float v  = (mat == 0) ? wh
             : (mat == 1) ? W0[j] * wh * sc
                          : W0[64 + j] * wh * sc;
    int R   = hd * 96 + mat * 32 + i;
    int off = (R * 128 + j * 2) ^ ((R & 7) << 4);
    *(unsigned short*)(sB + off) = (unsigned short)f2bfbits(v);
  }
  if (threadIdx.x < 96){
    int hd = threadIdx.x >> 5, row = threadIdx.x & 31;
    const float* BH = (hd == 0) ? bh1 : (hd == 1) ? bh2 : bh3;
    const float* WO = (hd == 0) ? Wo1 : (hd == 1) ? Wo2 : Wo3;
    sBH[threadIdx.x] = BH[row];
    sWO[threadIdx.x] = WO[row];
  }
  __syncthreads();

  const int wv   = threadIdx.x >> 6;
  const int lane = threadIdx.x & 63;
  const int colL = lane & 15;
  const int grp  = lane >> 4;
  char* sAw = &sA[wv][0];

  float bo_v[3] = {bo1[0], bo2[0], bo3[0]};

  const int gid = blockIdx.x * NB + threadIdx.x;
  const int ii  = (gid < n) ? gid : (n - 1);
  const float valid = (gid < n) ? 1.0f : 0.0f;

  const float2 yv = ((const float2*)Y)[ii];
  const float y2 = yv.x, y3 = yv.y;

  const float GAMMA = 1.2f, DT = 0.005f, SIGMA = 0.03f;
  const float KAPPA = 0.2f, YBAR = 2.0f, RHO = 0.03f, Bc = 1.0f, Cc = 0.1f;

  float q1,q2,q3,s11,s21,s31,s12,s22,s32;
  net_eval(y2, y3, W0, b0, sAw, sB, sBH, sWO, colL, grp, bo_v,
           q1,q2,q3,s11,s21,s31,s12,s22,s32);
  float Y2 = y2, Y3 = y3;
  float loss = 0.0f;

  for (int t = 0; t < PERIOD; ++t){
    // --- noise: threefry rollout, counter = flat index (bit-exact) ---
    uint32_t idx0 = 2u * ((uint32_t)t * (uint32_t)n + (uint32_t)ii);
    uint32_t a0, a1, c0, c1;
    threefry2x32_k42(0u, idx0,      a0, a1);
    threefry2x32_k42(0u, idx0 + 1u, c0, c1);
    float dZ1 = 0.070710678f * normal_from_bits(a0 ^ a1);
    float dZ2 = 0.070710678f * normal_from_bits(c0 ^ c1);

    // --- step math (mirror reference, f32) ---
    float Wt  = q1 + q2 + q3;
    float q1h = q1 / Wt;
    float q2h = q2 / Wt;
    float q3h = 1.0f - q1h - q2h;
    float q1sq = q1 * q1;
    float c   = Bc*q1 - Cc*q1sq + Y2 + Y3;
    float bq  = Bc*q1 - 2.0f*Cc*q1sq;
    float sc1 = fmaf(bq, s11, SIGMA);
    float sc2 = fmaf(bq, s12, SIGMA);
    float sW1 = q1*s11 + q2*s21 + q3*s31;
    float sW2 = q1*s12 + q2*s22 + q3*s32;
    float sJ1 = 6.0f * (sc1/c - sW1/Wt);
    float sJ2 = 6.0f * (sc2/c - sW2/Wt);
    float d11 = s11*s11 + s12*s12;
    float d12 = s11*s21 + s12*s22;
    float d13 = s11*s31 + s12*s32;
    float d22 = s21*s21 + s22*s22;
    float d23 = s21*s31 + s22*s32;
    float d33 = s31*s31 + s32*s32;
    const float oneMG = 1.0f - GAMMA;   // -0.2
    float p1 = GAMMA*(q1h*d11 + q2h*d12 + q3h*d13) - oneMG*(sJ1*s11 + sJ2*s12);
    float p2 = GAMMA*(q1h*d12 + q2h*d22 + q3h*d23) - oneMG*(sJ1*s21 + sJ2*s22);
    float p3 = GAMMA*(q1h*d13 + q2h*d23 + q3h*d33) - oneMG*(sJ1*s31 + sJ2*s32);
    float muY2 = KAPPA * (YBAR - Y2);
    float muY3 = KAPPA * (YBAR - Y3);
    float r = RHO + GAMMA*(bq*(p1 - (Bc - Cc*q1)) - Cc*q1sq*d11 + muY2 + muY3)/c
                  - 1.32f*(sc1*sc1 + sc2*sc2)/(c*c);
    r = r / (1.0f - GAMMA*bq/c);
    float mu1 = r + p1 - (Bc - Cc*q1);
    float mu2 = r + p2 - Y2/q2;
    float mu3 = r + p3 - Y3/q3;
    float q1n = q1 * (1.0f + mu1*DT + s11*dZ1 + s12*dZ2);
    float q2n = q2 * (1.0f + mu2*DT + s21*dZ1 + s22*dZ2);
    float q3n = q3 * (1.0f + mu3*DT + s31*dZ1 + s32*dZ2);
    float Y2n = Y2 + muY2*DT + SIGMA*dZ1;
    float Y3n = Y3 + muY3*DT + SIGMA*dZ2;

    float qt1, qt2, qt3;
    net_eval(Y2n, Y3n, W0, b0, sAw, sB, sBH, sWO, colL, grp, bo_v,
             qt1,qt2,qt3, s11,s21,s31,s12,s22,s32);

    float e1 = q1n - qt1, e2 = q2n - qt2, e3 = q3n - qt3;
    loss += e1*e1 + e2*e2 + e3*e3;

    q1 = q1n; q2 = q2n; q3 = q3n; Y2 = Y2n; Y3 = Y3n;
  }

  loss *= valid * (1.0f / ((float)15000000));   // / (n * PERIOD)

  // --- block reduction -> one atomic per block ---
#pragma unroll
  for (int off = 32; off > 0; off >>= 1)
    loss += __shfl_down(loss, off, 64);
  __shared__ float sred[NB / 64];
  if (lane == 0) sred[wv] = loss;
  __syncthreads();
  if (threadIdx.x == 0){
    float s = 0.0f;
#pragma unroll
    for (int w = 0; w < NB / 64; ++w) s += sred[w];
    atomicAdd(out, s);
  }
}

extern "C" void kernel_launch(void* const* d_in, const int* in_sizes, int n_in,
                              void* d_out, int out_size, void* d_ws, size_t ws_size,
                              hipStream_t stream)
{
  const float* Y   = (const float*)d_in[0];
  const float* W0  = (const float*)d_in[1];
  const float* b0  = (const float*)d_in[2];
  const float* Wh1 = (const float*)d_in[3];
  const float* bh1 = (const float*)d_in[4];
  const float* Wo1 = (const float*)d_in[5];
  const float* bo1 = (const float*)d_in[6];
  const float* Wh2 = (const float*)d_in[7];
  const float* bh2 = (const float*)d_in[8];
  const float* Wo2 = (const float*)d_in[9];
  const float* bo2 = (const float*)d_in[10];
  const float* Wh3 = (const float*)d_in[11];
  const float* bh3 = (const float*)d_in[12];
  const float* Wo3 = (const float*)d_in[13];
  const float* bo3 = (const float*)d_in[14];

  const int n = in_sizes[0] / 2;

  (void)hipMemsetAsync(d_out, 0, sizeof(float), stream);

  const int grid = (n + NB - 1) / NB;
  sim_kernel<<<grid, NB, 0, stream>>>(Y,
      W0, b0, Wh1, bh1, Wo1, bo1, Wh2, bh2, Wo2, bo2, Wh3, bh3, Wo3, bo3,
      (float*)d_out, n);
}